// Round 1
// baseline (2135.618 us; speedup 1.0000x reference)
//
#include <hip/hip_runtime.h>
#include <hip/hip_bf16.h>
#include <cstdint>

namespace {
constexpr int B  = 32;
constexpr int L  = 512;
constexpr int D  = 256;
constexpr int H  = 8;
constexpr int DK = 32;
constexpr int DV = 32;
constexpr int DFF = 2048;
constexpr int CONCAT = D * H * DV + D;   // 65792
constexpr int BH = B * H;                // 256
}

// ---------------- QKV projection: (B*L, 256) @ (256, 256) -> (BH, L, 32) ----------------
// Block: 32 rows x 256 cols, 256 threads (thread = col). Output written in (B,H,L,DK) layout.
__global__ __launch_bounds__(256) void proj_kernel(const float* __restrict__ A,
                                                   const float* __restrict__ W,
                                                   float* __restrict__ out) {
    const int rb = blockIdx.x * 32;      // global row base (b*512 + l0)
    const int t  = threadIdx.x;
    __shared__ float As[32][33];
    __shared__ float Ws[32][256];
    float acc[32];
#pragma unroll
    for (int r = 0; r < 32; ++r) acc[r] = 0.f;

    for (int kc = 0; kc < 8; ++kc) {
        const int k0 = kc * 32;
        __syncthreads();
#pragma unroll
        for (int p = 0; p < 4; ++p) {
            int idx = t + p * 256;
            int r = idx >> 5, c = idx & 31;
            As[r][c] = A[(size_t)(rb + r) * 256 + k0 + c];
        }
#pragma unroll
        for (int p = 0; p < 32; ++p) {
            int idx = t + p * 256;
            int k = idx >> 8, n = idx & 255;
            Ws[k][n] = W[(size_t)(k0 + k) * 256 + n];
        }
        __syncthreads();
#pragma unroll 8
        for (int k = 0; k < 32; ++k) {
            float wv = Ws[k][t];
#pragma unroll
            for (int r = 0; r < 32; ++r) acc[r] += As[r][k] * wv;
        }
    }
    const int h = t >> 5, d = t & 31;
    const int b = rb >> 9;        // rb / 512
    const int l0 = rb & 511;
    float* ob = out + ((size_t)(b * H + h)) * L * 32;
#pragma unroll
    for (int r = 0; r < 32; ++r) ob[(size_t)(l0 + r) * 32 + d] = acc[r];
}

// ---------------- Attention: per (bh, 32-q tile) ----------------
// scores in LDS [32][513] (513 => bank = (q + k) % 32, conflict-free in both phases)
__global__ __launch_bounds__(256) void attn_kernel(const float* __restrict__ Q,
                                                   const float* __restrict__ K,
                                                   const float* __restrict__ V,
                                                   const int* __restrict__ amask,
                                                   float* __restrict__ attn_out,
                                                   float* __restrict__ ctx) {
    const int qt = blockIdx.x;           // 0..15
    const int bh = blockIdx.y;           // 0..255
    const int b = bh >> 3, h = bh & 7;
    const int q0 = qt * 32;
    const int t = threadIdx.x;

    __shared__ float s_sc[32][513];
    __shared__ float s_q[32][32];
    __shared__ float s_kv[32 * 65];      // Kt[32][65] (2080) / Vs[64][32] (2048) union
    __shared__ float s_rinv[32];

    const float scale = 0.17677669529663687f;   // 1/sqrt(32)

    // Q tile: 32x32 contiguous
    const float* Qb = Q + ((size_t)bh * L + q0) * 32;
#pragma unroll
    for (int p = 0; p < 4; ++p) {
        int idx = t + p * 256;
        s_q[idx >> 5][idx & 31] = Qb[idx];
    }
    __syncthreads();

    // ---- scores ----
    const int kl = t & 63;   // k within chunk
    const int qg = t >> 6;   // q group (4 waves)
    const float* Kb = K + (size_t)bh * L * 32;
    for (int kc = 0; kc < 8; ++kc) {
        const int kbase = kc * 64;
        __syncthreads();
#pragma unroll
        for (int p = 0; p < 8; ++p) {
            int idx = t + p * 256;
            int kk = idx >> 5, d = idx & 31;
            s_kv[d * 65 + kk] = Kb[(size_t)(kbase + kk) * 32 + d];   // transposed stage
        }
        __syncthreads();
        for (int qq = qg; qq < 32; qq += 4) {
            float s = 0.f;
#pragma unroll
            for (int d = 0; d < 32; ++d) s += s_q[qq][d] * s_kv[d * 65 + kl];
            s *= scale;
            int kglob = kbase + kl;
            int m = amask[((size_t)b * L + (q0 + qq)) * L + kglob];
            s_sc[qq][kglob] = m ? -1e9f : s;
        }
    }
    __syncthreads();

    // ---- softmax (wave w handles rows w*8 .. w*8+7) ----
    const int w = t >> 6, lane = t & 63;
    for (int rr = 0; rr < 8; ++rr) {
        const int q = w * 8 + rr;
        float v[8];
        float m = -3.4e38f;
#pragma unroll
        for (int j = 0; j < 8; ++j) { v[j] = s_sc[q][lane + j * 64]; m = fmaxf(m, v[j]); }
#pragma unroll
        for (int o = 1; o < 64; o <<= 1) m = fmaxf(m, __shfl_xor(m, o));
        float sum = 0.f;
#pragma unroll
        for (int j = 0; j < 8; ++j) { v[j] = __expf(v[j] - m); sum += v[j]; }
#pragma unroll
        for (int o = 1; o < 64; o <<= 1) sum += __shfl_xor(sum, o);
        float rinv = 1.f / sum;
        float* ao = attn_out + ((size_t)bh * L + (q0 + q)) * L;
#pragma unroll
        for (int j = 0; j < 8; ++j) {
            s_sc[q][lane + j * 64] = v[j];            // unnormalized exp kept in LDS
            ao[lane + j * 64] = v[j] * rinv;          // normalized to global
        }
        if (lane == 0) s_rinv[q] = rinv;
    }
    __syncthreads();

    // ---- context: ctx[q][d] = sum_k p * V ----
    const float* Vb = V + (size_t)bh * L * 32;
    const int cq = t & 31;       // q row
    const int dg = t >> 5;       // 0..7, each owns 4 d
    float a0 = 0.f, a1 = 0.f, a2 = 0.f, a3 = 0.f;
    for (int kc = 0; kc < 8; ++kc) {
        const int kbase = kc * 64;
        __syncthreads();
#pragma unroll
        for (int p = 0; p < 8; ++p) {
            int idx = t + p * 256;
            int kk = idx >> 5, d = idx & 31;
            s_kv[kk * 32 + d] = Vb[(size_t)(kbase + kk) * 32 + d];
        }
        __syncthreads();
        for (int kk = 0; kk < 64; ++kk) {
            float pv = s_sc[cq][kbase + kk];
            const float* vr = &s_kv[kk * 32 + dg * 4];
            a0 += pv * vr[0]; a1 += pv * vr[1]; a2 += pv * vr[2]; a3 += pv * vr[3];
        }
    }
    const float rinv = s_rinv[cq];
    float* co = ctx + (((size_t)b * L + (q0 + cq)) * 256 + h * 32 + dg * 4);
    co[0] = a0 * rinv; co[1] = a1 * rinv; co[2] = a2 * rinv; co[3] = a3 * rinv;
}

// ---------------- column softmax over L for ctx -> weights ----------------
__global__ __launch_bounds__(256) void wts_kernel(const float* __restrict__ ctx,
                                                  const int* __restrict__ imask,
                                                  float* __restrict__ wts) {
    const int b = blockIdx.x >> 2;
    const int ct = blockIdx.x & 3;
    const int t = threadIdx.x;
    const int c = ct * 64 + (t & 63);
    const int g = t >> 6;
    __shared__ float red[4][64];
    __shared__ int mk[L];
    for (int p = t; p < L; p += 256) mk[p] = imask[b * L + p];
    __syncthreads();

    float m = -3.4e38f;
    for (int l = g; l < L; l += 4) {
        float v = mk[l] ? ctx[((size_t)b * L + l) * 256 + c] : -1e9f;
        m = fmaxf(m, v);
    }
    red[g][t & 63] = m;
    __syncthreads();
    m = fmaxf(fmaxf(red[0][t & 63], red[1][t & 63]), fmaxf(red[2][t & 63], red[3][t & 63]));

    float sum = 0.f;
    for (int l = g; l < L; l += 4) {
        float v = mk[l] ? ctx[((size_t)b * L + l) * 256 + c] : -1e9f;
        sum += __expf(v - m);
    }
    __syncthreads();
    red[g][t & 63] = sum;
    __syncthreads();
    sum = red[0][t & 63] + red[1][t & 63] + red[2][t & 63] + red[3][t & 63];
    const float rinv = 1.f / sum;

    for (int l = g; l < L; l += 4) {
        float v = mk[l] ? ctx[((size_t)b * L + l) * 256 + c] : -1e9f;
        wts[((size_t)b * L + l) * 256 + c] = __expf(v - m) * rinv;
    }
}

// ---------------- pooled: per-b GEMM emb^T (256x512) @ wts (512x256), write x^T ----------------
__global__ __launch_bounds__(256) void pooled_kernel(const float* __restrict__ emb,
                                                     const float* __restrict__ wts,
                                                     float* __restrict__ xT) {
    const int ct = blockIdx.x;    // c tile (64)
    const int dt = blockIdx.y;    // d tile (64)
    const int b  = blockIdx.z;
    const int t = threadIdx.x;
    __shared__ float Es[32][65];
    __shared__ float Ws2[32][65];
    const int tr = t >> 4, tc = t & 15;
    float acc[4][4];
#pragma unroll
    for (int i = 0; i < 4; ++i)
#pragma unroll
        for (int j = 0; j < 4; ++j) acc[i][j] = 0.f;

    for (int lc = 0; lc < 16; ++lc) {
        const int l0 = lc * 32;
        __syncthreads();
#pragma unroll
        for (int p = 0; p < 8; ++p) {
            int idx = t + p * 256;
            int i = idx >> 6, j = idx & 63;
            Es[i][j]  = emb[((size_t)b * L + l0 + i) * 256 + dt * 64 + j];
            Ws2[i][j] = wts[((size_t)b * L + l0 + i) * 256 + ct * 64 + j];
        }
        __syncthreads();
#pragma unroll 8
        for (int i = 0; i < 32; ++i) {
            float a0 = Es[i][tr * 4 + 0], a1 = Es[i][tr * 4 + 1], a2 = Es[i][tr * 4 + 2], a3 = Es[i][tr * 4 + 3];
            float w0 = Ws2[i][tc * 4 + 0], w1 = Ws2[i][tc * 4 + 1], w2 = Ws2[i][tc * 4 + 2], w3 = Ws2[i][tc * 4 + 3];
            acc[0][0] += a0 * w0; acc[0][1] += a0 * w1; acc[0][2] += a0 * w2; acc[0][3] += a0 * w3;
            acc[1][0] += a1 * w0; acc[1][1] += a1 * w1; acc[1][2] += a1 * w2; acc[1][3] += a1 * w3;
            acc[2][0] += a2 * w0; acc[2][1] += a2 * w1; acc[2][2] += a2 * w2; acc[2][3] += a2 * w3;
            acc[3][0] += a3 * w0; acc[3][1] += a3 * w1; acc[3][2] += a3 * w2; acc[3][3] += a3 * w3;
        }
    }
#pragma unroll
    for (int i = 0; i < 4; ++i)
#pragma unroll
        for (int j = 0; j < 4; ++j) {
            int d = dt * 64 + tr * 4 + i;
            int c = ct * 64 + tc * 4 + j;
            xT[((size_t)(d * 256 + c)) * 32 + b] = acc[i][j];
        }
}

// ---------------- avg_emb -> tail of x^T ----------------
__global__ __launch_bounds__(256) void avg_kernel(const float* __restrict__ emb,
                                                  const int* __restrict__ imask,
                                                  float* __restrict__ xT) {
    const int b = blockIdx.x;
    const int d = threadIdx.x;
    float s = 0.f;
    int cnt = 0;
    for (int l = 0; l < L; ++l) {
        int m = imask[b * L + l];
        cnt += m;
        if (m) s += emb[((size_t)b * L + l) * 256 + d];
    }
    float len = (float)(cnt > 0 ? cnt : 1);
    xT[((size_t)(D * H * DV + d)) * 32 + b] = s / len;
}

// ---------------- split-K fc: xT (K x 32) @ W (K x ncols) -> partials[kc][b][col] ----------------
// Each thread: 2 columns, 32 batch accumulators each.
__global__ __launch_bounds__(256) void fcsplit_kernel(const float* __restrict__ xT,
                                                      const float* __restrict__ Wf,
                                                      float* __restrict__ part,
                                                      int Ktot, int CH, int ncols) {
    const int ct = blockIdx.x;
    const int kc = blockIdx.y;
    const int t = threadIdx.x;
    const int col0 = ct * 512 + t;               // col0 and col0+256
    const size_t k0 = (size_t)kc * CH;
    const int klen = min(CH, Ktot - (int)k0);
    __shared__ float xs[128][32];
    float acc0[32], acc1[32];
#pragma unroll
    for (int b = 0; b < 32; ++b) { acc0[b] = 0.f; acc1[b] = 0.f; }

    for (int ks = 0; ks < klen; ks += 128) {
        const int kl = min(128, klen - ks);
        __syncthreads();
        for (int p = t; p < kl * 32; p += 256) xs[p >> 5][p & 31] = xT[(k0 + ks) * 32 + p];
        __syncthreads();
        const float* wp = Wf + (k0 + ks) * ncols;
        for (int kk = 0; kk < kl; ++kk) {
            float w0 = wp[(size_t)kk * ncols + col0];
            float w1 = wp[(size_t)kk * ncols + col0 + 256];
            const float4* xr = reinterpret_cast<const float4*>(xs[kk]);
#pragma unroll
            for (int i = 0; i < 8; ++i) {
                float4 xv = xr[i];
                acc0[i * 4 + 0] += xv.x * w0; acc0[i * 4 + 1] += xv.y * w0;
                acc0[i * 4 + 2] += xv.z * w0; acc0[i * 4 + 3] += xv.w * w0;
                acc1[i * 4 + 0] += xv.x * w1; acc1[i * 4 + 1] += xv.y * w1;
                acc1[i * 4 + 2] += xv.z * w1; acc1[i * 4 + 3] += xv.w * w1;
            }
        }
    }
    float* pp = part + (size_t)kc * 32 * ncols;
#pragma unroll
    for (int b = 0; b < 32; ++b) {
        pp[(size_t)b * ncols + col0] = acc0[b];
        pp[(size_t)b * ncols + col0 + 256] = acc1[b];
    }
}

// ---------------- reduce partials -> out^T (ncols x 32), bias + relu ----------------
__global__ __launch_bounds__(256) void fcreduce_kernel(const float* __restrict__ part,
                                                       const float* __restrict__ bias,
                                                       float* __restrict__ outT,
                                                       int nkc) {
    const int o = blockIdx.x * 256 + threadIdx.x;     // o in [0, 65536): b*2048 + col
    float s = 0.f;
    for (int kc = 0; kc < nkc; ++kc) s += part[(size_t)kc * 65536 + o];
    const int b = o >> 11, col = o & 2047;
    s += bias[col];
    s = fmaxf(s, 0.f);
    outT[(size_t)col * 32 + b] = s;
}

// ---------------- fc3: h2T (2048 x 32) @ w3 (2048) -> out (32) ----------------
__global__ __launch_bounds__(256) void fc3_kernel(const float* __restrict__ h2T,
                                                  const float* __restrict__ w3,
                                                  const float* __restrict__ b3,
                                                  float* __restrict__ out) {
    const int t = threadIdx.x;
    const int b = t & 31, p = t >> 5;
    float s = 0.f;
    for (int k = p; k < DFF; k += 8) s += h2T[(size_t)k * 32 + b] * w3[k];
    __shared__ float red[8][32];
    red[p][b] = s;
    __syncthreads();
    if (t < 32) {
        float tot = 0.f;
#pragma unroll
        for (int q = 0; q < 8; ++q) tot += red[q][t];
        out[t] = tot + b3[0];
    }
}

extern "C" void kernel_launch(void* const* d_in, const int* in_sizes, int n_in,
                              void* d_out, int out_size, void* d_ws, size_t ws_size,
                              hipStream_t stream) {
    const float* emb   = (const float*)d_in[0];
    const int*   amask = (const int*)d_in[1];
    const int*   imask = (const int*)d_in[2];
    const float* WQ    = (const float*)d_in[3];
    const float* WK    = (const float*)d_in[4];
    const float* WV    = (const float*)d_in[5];
    const float* fc1w  = (const float*)d_in[6];
    const float* fc1b  = (const float*)d_in[7];
    const float* fc2w  = (const float*)d_in[8];
    const float* fc2b  = (const float*)d_in[9];
    const float* fc3w  = (const float*)d_in[10];
    const float* fc3b  = (const float*)d_in[11];

    float* out_head = (float*)d_out;           // 32 floats
    float* attn_out = out_head + 32;           // (BH, L, L)

    float* ws = (float*)d_ws;
    const size_t SZ_PROJ = (size_t)BH * L * 32;     // 4,194,304
    float* Qb   = ws;                    // proj outputs
    float* Kb   = Qb + SZ_PROJ;
    float* Vb   = Kb + SZ_PROJ;
    float* ctx  = Vb + SZ_PROJ;          // (B, L, 256)
    float* wtsb = ctx + SZ_PROJ;         // (B, L, 256)
    float* xT   = wtsb + SZ_PROJ;        // (65792, 32)
    float* part1 = xT + (size_t)CONCAT * 32;           // 65 * 65536
    float* h1T   = part1 + (size_t)65 * 65536;          // (2048, 32)
    float* part2 = h1T + (size_t)DFF * 32;              // 32 * 65536
    float* h2T   = part2 + (size_t)32 * 65536;          // (2048, 32)

    // QKV projections
    proj_kernel<<<dim3(512), 256, 0, stream>>>(emb, WQ, Qb);
    proj_kernel<<<dim3(512), 256, 0, stream>>>(emb, WK, Kb);
    proj_kernel<<<dim3(512), 256, 0, stream>>>(emb, WV, Vb);

    // attention (writes attn_out + ctx)
    attn_kernel<<<dim3(16, BH), 256, 0, stream>>>(Qb, Kb, Vb, amask, attn_out, ctx);

    // column softmax over L
    wts_kernel<<<dim3(B * 4), 256, 0, stream>>>(ctx, imask, wtsb);

    // pooled einsum -> xT, avg_emb -> xT tail
    pooled_kernel<<<dim3(4, 4, B), 256, 0, stream>>>(emb, wtsb, xT);
    avg_kernel<<<dim3(B), 256, 0, stream>>>(emb, imask, xT);

    // fc1: K=65792, CH=1024 -> 65 chunks
    fcsplit_kernel<<<dim3(4, 65), 256, 0, stream>>>(xT, fc1w, part1, CONCAT, 1024, DFF);
    fcreduce_kernel<<<dim3(256), 256, 0, stream>>>(part1, fc1b, h1T, 65);

    // fc2: K=2048, CH=64 -> 32 chunks
    fcsplit_kernel<<<dim3(4, 32), 256, 0, stream>>>(h1T, fc2w, part2, DFF, 64, DFF);
    fcreduce_kernel<<<dim3(256), 256, 0, stream>>>(part2, fc2b, h2T, 32);

    // fc3
    fc3_kernel<<<dim3(1), 256, 0, stream>>>(h2T, fc3w, fc3b, out_head);
}

// Round 2
// 1267.512 us; speedup vs baseline: 1.6849x; 1.6849x over previous
//
#include <hip/hip_runtime.h>
#include <hip/hip_bf16.h>
#include <cstdint>

namespace {
constexpr int B  = 32;
constexpr int L  = 512;
constexpr int D  = 256;
constexpr int H  = 8;
constexpr int DV = 32;
constexpr int DFF = 2048;
constexpr int CONCAT = D * H * DV + D;   // 65792
constexpr int BH = B * H;                // 256
}

typedef __attribute__((ext_vector_type(8))) short bf16x8;
typedef __attribute__((ext_vector_type(4))) float f32x4;

static __device__ __forceinline__ unsigned short f2bf_bits(float x) {
    __hip_bfloat16 h = __float2bfloat16(x);
    return *reinterpret_cast<unsigned short*>(&h);
}

// ---------------- Fused QKV projection ----------------
// (B*L,256)@(256,256) x3. Block: 32 rows, 256 threads (thread = out col).
// Outputs: Q,K bf16 (BH,L,32) row-major; V bf16 transposed (BH,32,L).
__global__ __launch_bounds__(256) void proj_fused(const float* __restrict__ A,
                                                  const float* __restrict__ WQ,
                                                  const float* __restrict__ WK,
                                                  const float* __restrict__ WV,
                                                  __hip_bfloat16* __restrict__ Qb,
                                                  __hip_bfloat16* __restrict__ Kb,
                                                  __hip_bfloat16* __restrict__ Vt) {
    const int rb = blockIdx.x * 32;
    const int t  = threadIdx.x;
    __shared__ float Ast[32][36];     // transposed A tile, 144B rows (16B aligned)
    __shared__ float Ws[32][256];
    float accQ[32], accK[32], accV[32];
#pragma unroll
    for (int r = 0; r < 32; ++r) { accQ[r] = 0.f; accK[r] = 0.f; accV[r] = 0.f; }

#define PROJ_ACC(WPTR, ACC)                                                          \
    __syncthreads();                                                                 \
    _Pragma("unroll")                                                                \
    for (int p = 0; p < 32; ++p) {                                                   \
        int idx = t + p * 256; int wk = idx >> 8, wn = idx & 255;                    \
        Ws[wk][wn] = WPTR[(size_t)(k0 + wk) * 256 + wn];                             \
    }                                                                                \
    __syncthreads();                                                                 \
    _Pragma("unroll 4")                                                              \
    for (int k = 0; k < 32; ++k) {                                                   \
        float wv = Ws[k][t];                                                         \
        const float4* ar = reinterpret_cast<const float4*>(&Ast[k][0]);              \
        _Pragma("unroll")                                                            \
        for (int i = 0; i < 8; ++i) {                                                \
            float4 a = ar[i];                                                        \
            ACC[4*i+0] += a.x * wv; ACC[4*i+1] += a.y * wv;                          \
            ACC[4*i+2] += a.z * wv; ACC[4*i+3] += a.w * wv;                          \
        }                                                                            \
    }

    for (int kc = 0; kc < 8; ++kc) {
        const int k0 = kc * 32;
        __syncthreads();
#pragma unroll
        for (int p = 0; p < 4; ++p) {
            int idx = t + p * 256;
            int r = idx >> 5, k = idx & 31;
            Ast[k][r] = A[(size_t)(rb + r) * 256 + k0 + k];
        }
        PROJ_ACC(WQ, accQ)
        PROJ_ACC(WK, accK)
        PROJ_ACC(WV, accV)
    }
#undef PROJ_ACC

    const int h = t >> 5, d = t & 31;
    const int b = rb >> 9, l0 = rb & 511;
    const int bh = b * H + h;
    __hip_bfloat16* qo = Qb + ((size_t)bh * L + l0) * 32 + d;
    __hip_bfloat16* ko = Kb + ((size_t)bh * L + l0) * 32 + d;
#pragma unroll
    for (int r = 0; r < 32; ++r) {
        qo[r * 32] = __float2bfloat16(accQ[r]);
        ko[r * 32] = __float2bfloat16(accK[r]);
    }
    // V transposed: lane owns 32 contiguous bf16 -> 4x uint4 stores
    unsigned int vv[16];
#pragma unroll
    for (int i = 0; i < 16; ++i)
        vv[i] = (unsigned int)f2bf_bits(accV[2*i]) | ((unsigned int)f2bf_bits(accV[2*i+1]) << 16);
    uint4* vp = reinterpret_cast<uint4*>(Vt + ((size_t)bh * 32 + d) * L + l0);
    vp[0] = make_uint4(vv[0],  vv[1],  vv[2],  vv[3]);
    vp[1] = make_uint4(vv[4],  vv[5],  vv[6],  vv[7]);
    vp[2] = make_uint4(vv[8],  vv[9],  vv[10], vv[11]);
    vp[3] = make_uint4(vv[12], vv[13], vv[14], vv[15]);
}

// ---------------- MFMA attention ----------------
// Block = (qtile of 64 rows, bh); 4 waves, wave w owns 16 q-rows.
// Fragment layouts (gfx950 16x16x32 bf16): A[i][k]: i=l&15, k=(l>>4)*8+j (8 contig);
// B[k][n]: n=l&15, k=(l>>4)*8+j; D[r]: row=(l>>4)*4+r, col=l&15.
__global__ __launch_bounds__(256, 2) void attn_mfma(const __hip_bfloat16* __restrict__ Q,
                                                    const __hip_bfloat16* __restrict__ K,
                                                    const __hip_bfloat16* __restrict__ Vt,
                                                    const int* __restrict__ amask,
                                                    float* __restrict__ attn_out,
                                                    float* __restrict__ ctx) {
    const int qt = blockIdx.x;           // 0..7
    const int bh = blockIdx.y;           // 0..255
    const int b = bh >> 3, h = bh & 7;
    const int t = threadIdx.x;
    const int w = t >> 6, l = t & 63;
    const int lr = l & 15, lg = l >> 4;
    const int q0 = qt * 64 + w * 16;

    __shared__ __hip_bfloat16 Pl[4][16][40];   // per-wave P chunk (16x32, pad->40)

    const float scale = 0.17677669529663687f;  // 1/sqrt(32)

    // Q A-fragment: one 16B load per lane
    const bf16x8 aq = *reinterpret_cast<const bf16x8*>(Q + ((size_t)bh * L + q0 + lr) * 32 + lg * 8);

    // ---- scores: 32 k-tiles of 16 ----
    f32x4 sc[32];
    const __hip_bfloat16* Kbase = K + (size_t)bh * L * 32;
#pragma unroll
    for (int kt = 0; kt < 32; ++kt) {
        bf16x8 bk = *reinterpret_cast<const bf16x8*>(Kbase + (size_t)(kt * 16 + lr) * 32 + lg * 8);
        sc[kt] = __builtin_amdgcn_mfma_f32_16x16x32_bf16(aq, bk, (f32x4){0.f,0.f,0.f,0.f}, 0, 0, 0);
    }

    // ---- mask + softmax (per r: row q0 + lg*4 + r), write normalized attn ----
    float rin[4];
#pragma unroll
    for (int r = 0; r < 4; ++r) {
        const int q = q0 + lg * 4 + r;
        const int* mp = amask + ((size_t)b * L + q) * L + lr;
        float mx = -3.4e38f;
#pragma unroll
        for (int kt = 0; kt < 32; ++kt) {
            float s = mp[kt * 16] ? -1e9f : sc[kt][r] * scale;
            sc[kt][r] = s;
            mx = fmaxf(mx, s);
        }
        mx = fmaxf(mx, __shfl_xor(mx, 1));
        mx = fmaxf(mx, __shfl_xor(mx, 2));
        mx = fmaxf(mx, __shfl_xor(mx, 4));
        mx = fmaxf(mx, __shfl_xor(mx, 8));
        float sum = 0.f;
#pragma unroll
        for (int kt = 0; kt < 32; ++kt) {
            float e = __expf(sc[kt][r] - mx);
            sc[kt][r] = e;                     // keep unnormalized exp for PV
            sum += e;
        }
        sum += __shfl_xor(sum, 1);
        sum += __shfl_xor(sum, 2);
        sum += __shfl_xor(sum, 4);
        sum += __shfl_xor(sum, 8);
        const float rinv = 1.f / sum;
        rin[r] = rinv;
        float* ao = attn_out + ((size_t)bh * L + q) * L + lr;
#pragma unroll
        for (int kt = 0; kt < 32; ++kt) ao[kt * 16] = sc[kt][r] * rinv;
    }

    // ---- PV: ctx[16 x 32] = P[16 x 512] @ V[512 x 32], 16 chunks of K=32 ----
    f32x4 acc0 = {0.f,0.f,0.f,0.f}, acc1 = {0.f,0.f,0.f,0.f};
    const __hip_bfloat16* Vb = Vt + (size_t)bh * 32 * L;
#pragma unroll
    for (int c = 0; c < 16; ++c) {
        // stage P chunk (tiles 2c, 2c+1) into per-wave LDS, transposing D->A layout
#pragma unroll
        for (int r = 0; r < 4; ++r) {
            Pl[w][lg * 4 + r][lr]      = __float2bfloat16(sc[2*c  ][r]);
            Pl[w][lg * 4 + r][16 + lr] = __float2bfloat16(sc[2*c+1][r]);
        }
        __syncthreads();   // write->read ordering (uniform across block)
        bf16x8 ap  = *reinterpret_cast<const bf16x8*>(&Pl[w][lr][lg * 8]);
        bf16x8 bv0 = *reinterpret_cast<const bf16x8*>(Vb + (size_t)lr        * L + c * 32 + lg * 8);
        bf16x8 bv1 = *reinterpret_cast<const bf16x8*>(Vb + (size_t)(16 + lr) * L + c * 32 + lg * 8);
        acc0 = __builtin_amdgcn_mfma_f32_16x16x32_bf16(ap, bv0, acc0, 0, 0, 0);
        acc1 = __builtin_amdgcn_mfma_f32_16x16x32_bf16(ap, bv1, acc1, 0, 0, 0);
        __syncthreads();   // reads done before next chunk's writes
    }
    float* cb = ctx + ((size_t)b * L + q0 + lg * 4) * 256 + h * 32;
#pragma unroll
    for (int r = 0; r < 4; ++r) {
        cb[r * 256 + lr]      = acc0[r] * rin[r];
        cb[r * 256 + 16 + lr] = acc1[r] * rin[r];
    }
}

// ---------------- column softmax over L for ctx -> weights ----------------
__global__ __launch_bounds__(256) void wts_kernel(const float* __restrict__ ctx,
                                                  const int* __restrict__ imask,
                                                  float* __restrict__ wts) {
    const int b = blockIdx.x >> 2;
    const int ct = blockIdx.x & 3;
    const int t = threadIdx.x;
    const int c = ct * 64 + (t & 63);
    const int g = t >> 6;
    __shared__ float red[4][64];
    __shared__ int mk[L];
    for (int p = t; p < L; p += 256) mk[p] = imask[b * L + p];
    __syncthreads();

    float m = -3.4e38f;
    for (int ll = g; ll < L; ll += 4) {
        float v = mk[ll] ? ctx[((size_t)b * L + ll) * 256 + c] : -1e9f;
        m = fmaxf(m, v);
    }
    red[g][t & 63] = m;
    __syncthreads();
    m = fmaxf(fmaxf(red[0][t & 63], red[1][t & 63]), fmaxf(red[2][t & 63], red[3][t & 63]));

    float sum = 0.f;
    for (int ll = g; ll < L; ll += 4) {
        float v = mk[ll] ? ctx[((size_t)b * L + ll) * 256 + c] : -1e9f;
        sum += __expf(v - m);
    }
    __syncthreads();
    red[g][t & 63] = sum;
    __syncthreads();
    sum = red[0][t & 63] + red[1][t & 63] + red[2][t & 63] + red[3][t & 63];
    const float rinv = 1.f / sum;

    for (int ll = g; ll < L; ll += 4) {
        float v = mk[ll] ? ctx[((size_t)b * L + ll) * 256 + c] : -1e9f;
        wts[((size_t)b * L + ll) * 256 + c] = __expf(v - m) * rinv;
    }
}

// ---------------- pooled: per-b GEMM emb^T (256x512) @ wts (512x256), write x^T ----------------
__global__ __launch_bounds__(256) void pooled_kernel(const float* __restrict__ emb,
                                                     const float* __restrict__ wts,
                                                     float* __restrict__ xT) {
    const int ct = blockIdx.x;
    const int dt = blockIdx.y;
    const int b  = blockIdx.z;
    const int t = threadIdx.x;
    __shared__ float Es[32][65];
    __shared__ float Ws2[32][65];
    const int tr = t >> 4, tc = t & 15;
    float acc[4][4];
#pragma unroll
    for (int i = 0; i < 4; ++i)
#pragma unroll
        for (int j = 0; j < 4; ++j) acc[i][j] = 0.f;

    for (int lc = 0; lc < 16; ++lc) {
        const int l0 = lc * 32;
        __syncthreads();
#pragma unroll
        for (int p = 0; p < 8; ++p) {
            int idx = t + p * 256;
            int i = idx >> 6, j = idx & 63;
            Es[i][j]  = emb[((size_t)b * L + l0 + i) * 256 + dt * 64 + j];
            Ws2[i][j] = wts[((size_t)b * L + l0 + i) * 256 + ct * 64 + j];
        }
        __syncthreads();
#pragma unroll 8
        for (int i = 0; i < 32; ++i) {
            float a0 = Es[i][tr*4+0], a1 = Es[i][tr*4+1], a2 = Es[i][tr*4+2], a3 = Es[i][tr*4+3];
            float w0 = Ws2[i][tc*4+0], w1 = Ws2[i][tc*4+1], w2 = Ws2[i][tc*4+2], w3 = Ws2[i][tc*4+3];
            acc[0][0] += a0*w0; acc[0][1] += a0*w1; acc[0][2] += a0*w2; acc[0][3] += a0*w3;
            acc[1][0] += a1*w0; acc[1][1] += a1*w1; acc[1][2] += a1*w2; acc[1][3] += a1*w3;
            acc[2][0] += a2*w0; acc[2][1] += a2*w1; acc[2][2] += a2*w2; acc[2][3] += a2*w3;
            acc[3][0] += a3*w0; acc[3][1] += a3*w1; acc[3][2] += a3*w2; acc[3][3] += a3*w3;
        }
    }
#pragma unroll
    for (int i = 0; i < 4; ++i)
#pragma unroll
        for (int j = 0; j < 4; ++j) {
            int d = dt * 64 + tr * 4 + i;
            int c = ct * 64 + tc * 4 + j;
            xT[((size_t)(d * 256 + c)) * 32 + b] = acc[i][j];
        }
}

// ---------------- avg_emb -> tail of x^T ----------------
__global__ __launch_bounds__(256) void avg_kernel(const float* __restrict__ emb,
                                                  const int* __restrict__ imask,
                                                  float* __restrict__ xT) {
    const int b = blockIdx.x;
    const int d = threadIdx.x;
    float s = 0.f;
    int cnt = 0;
    for (int ll = 0; ll < L; ++ll) {
        int m = imask[b * L + ll];
        cnt += m;
        if (m) s += emb[((size_t)b * L + ll) * 256 + d];
    }
    float len = (float)(cnt > 0 ? cnt : 1);
    xT[((size_t)(D * H * DV + d)) * 32 + b] = s / len;
}

// ---------------- split-K fc: xT (K x 32) @ W (K x ncols) -> partials ----------------
__global__ __launch_bounds__(256) void fcsplit_kernel(const float* __restrict__ xT,
                                                      const float* __restrict__ Wf,
                                                      float* __restrict__ part,
                                                      int Ktot, int CH, int ncols) {
    const int ct = blockIdx.x;
    const int kc = blockIdx.y;
    const int t = threadIdx.x;
    const int col0 = ct * 512 + 2 * t;            // two adjacent columns
    const size_t k0 = (size_t)kc * CH;
    const int klen = min(CH, Ktot - (int)k0);
    __shared__ float xs[128][32];
    float acc0[32], acc1[32];
#pragma unroll
    for (int b = 0; b < 32; ++b) { acc0[b] = 0.f; acc1[b] = 0.f; }

    for (int ks = 0; ks < klen; ks += 128) {
        const int kl = min(128, klen - ks);
        __syncthreads();
        for (int p = t; p < kl * 32; p += 256) xs[p >> 5][p & 31] = xT[(k0 + ks) * 32 + p];
        __syncthreads();
        const float* wp = Wf + (k0 + ks) * ncols;
        for (int kk = 0; kk < kl; ++kk) {
            float2 wv = *reinterpret_cast<const float2*>(&wp[(size_t)kk * ncols + col0]);
            const float4* xr = reinterpret_cast<const float4*>(xs[kk]);
#pragma unroll
            for (int i = 0; i < 8; ++i) {
                float4 xv = xr[i];
                acc0[i*4+0] += xv.x * wv.x; acc0[i*4+1] += xv.y * wv.x;
                acc0[i*4+2] += xv.z * wv.x; acc0[i*4+3] += xv.w * wv.x;
                acc1[i*4+0] += xv.x * wv.y; acc1[i*4+1] += xv.y * wv.y;
                acc1[i*4+2] += xv.z * wv.y; acc1[i*4+3] += xv.w * wv.y;
            }
        }
    }
    float* pp = part + (size_t)kc * 32 * ncols;
#pragma unroll
    for (int b = 0; b < 32; ++b) {
        float2 o; o.x = acc0[b]; o.y = acc1[b];
        *reinterpret_cast<float2*>(&pp[(size_t)b * ncols + col0]) = o;
    }
}

// ---------------- reduce partials -> out^T (ncols x 32), bias + relu ----------------
__global__ __launch_bounds__(256) void fcreduce_kernel(const float* __restrict__ part,
                                                       const float* __restrict__ bias,
                                                       float* __restrict__ outT,
                                                       int nkc) {
    const int o = blockIdx.x * 256 + threadIdx.x;
    float s = 0.f;
    for (int kc = 0; kc < nkc; ++kc) s += part[(size_t)kc * 65536 + o];
    const int b = o >> 11, col = o & 2047;
    s += bias[col];
    s = fmaxf(s, 0.f);
    outT[(size_t)col * 32 + b] = s;
}

// ---------------- fc3 ----------------
__global__ __launch_bounds__(256) void fc3_kernel(const float* __restrict__ h2T,
                                                  const float* __restrict__ w3,
                                                  const float* __restrict__ b3,
                                                  float* __restrict__ out) {
    const int t = threadIdx.x;
    const int b = t & 31, p = t >> 5;
    float s = 0.f;
    for (int k = p; k < DFF; k += 8) s += h2T[(size_t)k * 32 + b] * w3[k];
    __shared__ float red[8][32];
    red[p][b] = s;
    __syncthreads();
    if (t < 32) {
        float tot = 0.f;
#pragma unroll
        for (int q = 0; q < 8; ++q) tot += red[q][t];
        out[t] = tot + b3[0];
    }
}

extern "C" void kernel_launch(void* const* d_in, const int* in_sizes, int n_in,
                              void* d_out, int out_size, void* d_ws, size_t ws_size,
                              hipStream_t stream) {
    const float* emb   = (const float*)d_in[0];
    const int*   amask = (const int*)d_in[1];
    const int*   imask = (const int*)d_in[2];
    const float* WQ    = (const float*)d_in[3];
    const float* WK    = (const float*)d_in[4];
    const float* WV    = (const float*)d_in[5];
    const float* fc1w  = (const float*)d_in[6];
    const float* fc1b  = (const float*)d_in[7];
    const float* fc2w  = (const float*)d_in[8];
    const float* fc2b  = (const float*)d_in[9];
    const float* fc3w  = (const float*)d_in[10];
    const float* fc3b  = (const float*)d_in[11];

    float* out_head = (float*)d_out;           // 32 floats
    float* attn_out = out_head + 32;           // (BH, L, L) fp32

    float* ws = (float*)d_ws;
    const size_t SZ_PROJ_BF = (size_t)BH * L * 32 / 2;   // bf16 buffers in float units (2,097,152)
    __hip_bfloat16* Qb = (__hip_bfloat16*)(ws);
    __hip_bfloat16* Kb = (__hip_bfloat16*)(ws + SZ_PROJ_BF);
    __hip_bfloat16* Vt = (__hip_bfloat16*)(ws + 2 * SZ_PROJ_BF);
    float* ctx   = ws + 3 * SZ_PROJ_BF;                      // (B,L,256) fp32
    float* wtsb  = ctx + (size_t)BH * L * 32;
    float* xT    = wtsb + (size_t)BH * L * 32;               // (65792, 32)
    float* part1 = xT + (size_t)CONCAT * 32;                 // 129 * 65536
    float* h1T   = part1 + (size_t)129 * 65536;
    float* part2 = h1T + (size_t)DFF * 32;                   // 32 * 65536
    float* h2T   = part2 + (size_t)32 * 65536;

    proj_fused<<<dim3(512), 256, 0, stream>>>(emb, WQ, WK, WV, Qb, Kb, Vt);

    attn_mfma<<<dim3(8, BH), 256, 0, stream>>>(Qb, Kb, Vt, amask, attn_out, ctx);

    wts_kernel<<<dim3(B * 4), 256, 0, stream>>>(ctx, imask, wtsb);

    pooled_kernel<<<dim3(4, 4, B), 256, 0, stream>>>(emb, wtsb, xT);
    avg_kernel<<<dim3(B), 256, 0, stream>>>(emb, imask, xT);

    fcsplit_kernel<<<dim3(4, 129), 256, 0, stream>>>(xT, fc1w, part1, CONCAT, 512, DFF);
    fcreduce_kernel<<<dim3(256), 256, 0, stream>>>(part1, fc1b, h1T, 129);

    fcsplit_kernel<<<dim3(4, 32), 256, 0, stream>>>(h1T, fc2w, part2, DFF, 64, DFF);
    fcreduce_kernel<<<dim3(256), 256, 0, stream>>>(part2, fc2b, h2T, 32);

    fc3_kernel<<<dim3(1), 256, 0, stream>>>(h2T, fc3w, fc3b, out_head);
}

// Round 3
// 919.985 us; speedup vs baseline: 2.3214x; 1.3778x over previous
//
#include <hip/hip_runtime.h>
#include <hip/hip_bf16.h>
#include <cstdint>

namespace {
constexpr int B  = 32;
constexpr int L  = 512;
constexpr int D  = 256;
constexpr int H  = 8;
constexpr int DV = 32;
constexpr int DFF = 2048;
constexpr int CONCAT = D * H * DV + D;   // 65792
constexpr int BH = B * H;                // 256
}

typedef __attribute__((ext_vector_type(8))) short bf16x8;
typedef __attribute__((ext_vector_type(4))) float f32x4;

static __device__ __forceinline__ unsigned short f2bf_bits(float x) {
    __hip_bfloat16 h = __float2bfloat16(x);
    return *reinterpret_cast<unsigned short*>(&h);
}
static __device__ __forceinline__ float bf2f(short u) {
    unsigned int x = ((unsigned int)(unsigned short)u) << 16;
    union { unsigned int u; float f; } c; c.u = x; return c.f;
}

// ---------------- mask bit-pack: (B,L,L) int32 -> (B,L,L/32) u32 via ballot ----------------
__global__ __launch_bounds__(256) void maskpack(const int* __restrict__ amask,
                                                unsigned int* __restrict__ mb) {
    const int t = threadIdx.x;
    const size_t gid = (size_t)blockIdx.x * 256 + t;
    int v = amask[gid];
    unsigned long long bal = __ballot(v != 0);
    if ((t & 63) == 0) *reinterpret_cast<unsigned long long*>(mb + (gid >> 5)) = bal;
}

// ---------------- Fused QKV projection ----------------
__global__ __launch_bounds__(256) void proj_fused(const float* __restrict__ A,
                                                  const float* __restrict__ WQ,
                                                  const float* __restrict__ WK,
                                                  const float* __restrict__ WV,
                                                  __hip_bfloat16* __restrict__ Qb,
                                                  __hip_bfloat16* __restrict__ Kb,
                                                  __hip_bfloat16* __restrict__ Vt) {
    const int rb = blockIdx.x * 32;
    const int t  = threadIdx.x;
    __shared__ float Ast[32][36];
    __shared__ float Ws[32][256];
    float accQ[32], accK[32], accV[32];
#pragma unroll
    for (int r = 0; r < 32; ++r) { accQ[r] = 0.f; accK[r] = 0.f; accV[r] = 0.f; }

#define PROJ_ACC(WPTR, ACC)                                                          \
    __syncthreads();                                                                 \
    _Pragma("unroll")                                                                \
    for (int p = 0; p < 32; ++p) {                                                   \
        int idx = t + p * 256; int wk = idx >> 8, wn = idx & 255;                    \
        Ws[wk][wn] = WPTR[(size_t)(k0 + wk) * 256 + wn];                             \
    }                                                                                \
    __syncthreads();                                                                 \
    _Pragma("unroll 4")                                                              \
    for (int k = 0; k < 32; ++k) {                                                   \
        float wv = Ws[k][t];                                                         \
        const float4* ar = reinterpret_cast<const float4*>(&Ast[k][0]);              \
        _Pragma("unroll")                                                            \
        for (int i = 0; i < 8; ++i) {                                                \
            float4 a = ar[i];                                                        \
            ACC[4*i+0] += a.x * wv; ACC[4*i+1] += a.y * wv;                          \
            ACC[4*i+2] += a.z * wv; ACC[4*i+3] += a.w * wv;                          \
        }                                                                            \
    }

    for (int kc = 0; kc < 8; ++kc) {
        const int k0 = kc * 32;
        __syncthreads();
#pragma unroll
        for (int p = 0; p < 4; ++p) {
            int idx = t + p * 256;
            int r = idx >> 5, k = idx & 31;
            Ast[k][r] = A[(size_t)(rb + r) * 256 + k0 + k];
        }
        PROJ_ACC(WQ, accQ)
        PROJ_ACC(WK, accK)
        PROJ_ACC(WV, accV)
    }
#undef PROJ_ACC

    const int h = t >> 5, d = t & 31;
    const int b = rb >> 9, l0 = rb & 511;
    const int bh = b * H + h;
    __hip_bfloat16* qo = Qb + ((size_t)bh * L + l0) * 32 + d;
    __hip_bfloat16* ko = Kb + ((size_t)bh * L + l0) * 32 + d;
#pragma unroll
    for (int r = 0; r < 32; ++r) {
        qo[r * 32] = __float2bfloat16(accQ[r]);
        ko[r * 32] = __float2bfloat16(accK[r]);
    }
    unsigned int vv[16];
#pragma unroll
    for (int i = 0; i < 16; ++i)
        vv[i] = (unsigned int)f2bf_bits(accV[2*i]) | ((unsigned int)f2bf_bits(accV[2*i+1]) << 16);
    uint4* vp = reinterpret_cast<uint4*>(Vt + ((size_t)bh * 32 + d) * L + l0);
    vp[0] = make_uint4(vv[0],  vv[1],  vv[2],  vv[3]);
    vp[1] = make_uint4(vv[4],  vv[5],  vv[6],  vv[7]);
    vp[2] = make_uint4(vv[8],  vv[9],  vv[10], vv[11]);
    vp[3] = make_uint4(vv[12], vv[13], vv[14], vv[15]);
}

// ---------------- MFMA attention (no block barriers; all LDS wave-private) ----------------
__global__ __launch_bounds__(256, 2) void attn_mfma(const __hip_bfloat16* __restrict__ Q,
                                                    const __hip_bfloat16* __restrict__ K,
                                                    const __hip_bfloat16* __restrict__ Vt,
                                                    const unsigned int* __restrict__ mb,
                                                    float* __restrict__ attn_out,
                                                    float* __restrict__ ctx) {
    const int qt = blockIdx.x;           // 0..7
    const int bh = blockIdx.y;           // 0..255
    const int b = bh >> 3, h = bh & 7;
    const int t = threadIdx.x;
    const int w = t >> 6, l = t & 63;
    const int lr = l & 15, lg = l >> 4;
    const int q0 = qt * 64 + w * 16;

    __shared__ __hip_bfloat16 Pl[4][16][40];
    __shared__ float s_ri[4][16];

    const float scale = 0.17677669529663687f;

    const bf16x8 aq = *reinterpret_cast<const bf16x8*>(Q + ((size_t)bh * L + q0 + lr) * 32 + lg * 8);

    f32x4 sc[32];
    const __hip_bfloat16* Kbase = K + (size_t)bh * L * 32;
#pragma unroll
    for (int kt = 0; kt < 32; ++kt) {
        bf16x8 bk = *reinterpret_cast<const bf16x8*>(Kbase + (size_t)(kt * 16 + lr) * 32 + lg * 8);
        sc[kt] = __builtin_amdgcn_mfma_f32_16x16x32_bf16(aq, bk, (f32x4){0.f,0.f,0.f,0.f}, 0, 0, 0);
    }

    float rin[4];
#pragma unroll
    for (int r = 0; r < 4; ++r) {
        const int q = q0 + lg * 4 + r;
        const uint4* mrow = reinterpret_cast<const uint4*>(mb + ((size_t)b * L + q) * 16);
        uint4 m0 = mrow[0], m1 = mrow[1], m2 = mrow[2], m3 = mrow[3];
        const unsigned int wds[16] = {m0.x, m0.y, m0.z, m0.w, m1.x, m1.y, m1.z, m1.w,
                                      m2.x, m2.y, m2.z, m2.w, m3.x, m3.y, m3.z, m3.w};
        float mx = -3.4e38f;
#pragma unroll
        for (int kt = 0; kt < 32; ++kt) {
            unsigned bit = (unsigned)lr + ((kt & 1) << 4);
            float s = ((wds[kt >> 1] >> bit) & 1u) ? -1e9f : sc[kt][r] * scale;
            sc[kt][r] = s;
            mx = fmaxf(mx, s);
        }
        mx = fmaxf(mx, __shfl_xor(mx, 1));
        mx = fmaxf(mx, __shfl_xor(mx, 2));
        mx = fmaxf(mx, __shfl_xor(mx, 4));
        mx = fmaxf(mx, __shfl_xor(mx, 8));
        float sum = 0.f;
#pragma unroll
        for (int kt = 0; kt < 32; ++kt) {
            float e = __expf(sc[kt][r] - mx);
            sc[kt][r] = e;
            sum += e;
        }
        sum += __shfl_xor(sum, 1);
        sum += __shfl_xor(sum, 2);
        sum += __shfl_xor(sum, 4);
        sum += __shfl_xor(sum, 8);
        rin[r] = 1.f / sum;
    }
    if (lr == 0) {
#pragma unroll
        for (int r = 0; r < 4; ++r) s_ri[w][lg * 4 + r] = rin[r];
    }
    const float my_ri = s_ri[w][lr];          // wave-local LDS RAW; compiler orders

    // ---- PV + fused normalized-attn store ----
    f32x4 acc0 = {0.f,0.f,0.f,0.f}, acc1 = {0.f,0.f,0.f,0.f};
    const __hip_bfloat16* Vb = Vt + (size_t)bh * 32 * L;
    float* aob = attn_out + ((size_t)bh * L + q0 + lr) * L;
#pragma unroll
    for (int c = 0; c < 16; ++c) {
#pragma unroll
        for (int r = 0; r < 4; ++r) {
            Pl[w][lg * 4 + r][lr]      = __float2bfloat16(sc[2*c  ][r]);
            Pl[w][lg * 4 + r][16 + lr] = __float2bfloat16(sc[2*c+1][r]);
        }
        bf16x8 ap  = *reinterpret_cast<const bf16x8*>(&Pl[w][lr][lg * 8]);
        float4 o0, o1;
        o0.x = bf2f(ap[0]) * my_ri; o0.y = bf2f(ap[1]) * my_ri;
        o0.z = bf2f(ap[2]) * my_ri; o0.w = bf2f(ap[3]) * my_ri;
        o1.x = bf2f(ap[4]) * my_ri; o1.y = bf2f(ap[5]) * my_ri;
        o1.z = bf2f(ap[6]) * my_ri; o1.w = bf2f(ap[7]) * my_ri;
        float* ao = aob + c * 32 + lg * 8;
        *reinterpret_cast<float4*>(ao)     = o0;
        *reinterpret_cast<float4*>(ao + 4) = o1;
        bf16x8 bv0 = *reinterpret_cast<const bf16x8*>(Vb + (size_t)lr        * L + c * 32 + lg * 8);
        bf16x8 bv1 = *reinterpret_cast<const bf16x8*>(Vb + (size_t)(16 + lr) * L + c * 32 + lg * 8);
        acc0 = __builtin_amdgcn_mfma_f32_16x16x32_bf16(ap, bv0, acc0, 0, 0, 0);
        acc1 = __builtin_amdgcn_mfma_f32_16x16x32_bf16(ap, bv1, acc1, 0, 0, 0);
    }
    float* cb = ctx + ((size_t)b * L + q0 + lg * 4) * 256 + h * 32;
#pragma unroll
    for (int r = 0; r < 4; ++r) {
        cb[r * 256 + lr]      = acc0[r] * rin[r];
        cb[r * 256 + 16 + lr] = acc1[r] * rin[r];
    }
}

// ---------------- column softmax over L for ctx -> weights ----------------
__global__ __launch_bounds__(256) void wts_kernel(const float* __restrict__ ctx,
                                                  const int* __restrict__ imask,
                                                  float* __restrict__ wts) {
    const int b = blockIdx.x >> 2;
    const int ct = blockIdx.x & 3;
    const int t = threadIdx.x;
    const int c = ct * 64 + (t & 63);
    const int g = t >> 6;
    __shared__ float red[4][64];
    __shared__ int mk[L];
    for (int p = t; p < L; p += 256) mk[p] = imask[b * L + p];
    __syncthreads();

    float m = -3.4e38f;
    for (int ll = g; ll < L; ll += 4) {
        float v = mk[ll] ? ctx[((size_t)b * L + ll) * 256 + c] : -1e9f;
        m = fmaxf(m, v);
    }
    red[g][t & 63] = m;
    __syncthreads();
    m = fmaxf(fmaxf(red[0][t & 63], red[1][t & 63]), fmaxf(red[2][t & 63], red[3][t & 63]));

    float sum = 0.f;
    for (int ll = g; ll < L; ll += 4) {
        float v = mk[ll] ? ctx[((size_t)b * L + ll) * 256 + c] : -1e9f;
        sum += __expf(v - m);
    }
    __syncthreads();
    red[g][t & 63] = sum;
    __syncthreads();
    sum = red[0][t & 63] + red[1][t & 63] + red[2][t & 63] + red[3][t & 63];
    const float rinv = 1.f / sum;

    for (int ll = g; ll < L; ll += 4) {
        float v = mk[ll] ? ctx[((size_t)b * L + ll) * 256 + c] : -1e9f;
        wts[((size_t)b * L + ll) * 256 + c] = __expf(v - m) * rinv;
    }
}

// ---------------- pooled: per-b GEMM emb^T @ wts -> x^T ----------------
__global__ __launch_bounds__(256) void pooled_kernel(const float* __restrict__ emb,
                                                     const float* __restrict__ wts,
                                                     float* __restrict__ xT) {
    const int ct = blockIdx.x;
    const int dt = blockIdx.y;
    const int b  = blockIdx.z;
    const int t = threadIdx.x;
    __shared__ float Es[32][65];
    __shared__ float Ws2[32][65];
    const int tr = t >> 4, tc = t & 15;
    float acc[4][4];
#pragma unroll
    for (int i = 0; i < 4; ++i)
#pragma unroll
        for (int j = 0; j < 4; ++j) acc[i][j] = 0.f;

    for (int lc = 0; lc < 16; ++lc) {
        const int l0 = lc * 32;
        __syncthreads();
#pragma unroll
        for (int p = 0; p < 8; ++p) {
            int idx = t + p * 256;
            int i = idx >> 6, j = idx & 63;
            Es[i][j]  = emb[((size_t)b * L + l0 + i) * 256 + dt * 64 + j];
            Ws2[i][j] = wts[((size_t)b * L + l0 + i) * 256 + ct * 64 + j];
        }
        __syncthreads();
#pragma unroll 8
        for (int i = 0; i < 32; ++i) {
            float a0 = Es[i][tr*4+0], a1 = Es[i][tr*4+1], a2 = Es[i][tr*4+2], a3 = Es[i][tr*4+3];
            float w0 = Ws2[i][tc*4+0], w1 = Ws2[i][tc*4+1], w2 = Ws2[i][tc*4+2], w3 = Ws2[i][tc*4+3];
            acc[0][0] += a0*w0; acc[0][1] += a0*w1; acc[0][2] += a0*w2; acc[0][3] += a0*w3;
            acc[1][0] += a1*w0; acc[1][1] += a1*w1; acc[1][2] += a1*w2; acc[1][3] += a1*w3;
            acc[2][0] += a2*w0; acc[2][1] += a2*w1; acc[2][2] += a2*w2; acc[2][3] += a2*w3;
            acc[3][0] += a3*w0; acc[3][1] += a3*w1; acc[3][2] += a3*w2; acc[3][3] += a3*w3;
        }
    }
#pragma unroll
    for (int i = 0; i < 4; ++i)
#pragma unroll
        for (int j = 0; j < 4; ++j) {
            int d = dt * 64 + tr * 4 + i;
            int c = ct * 64 + tc * 4 + j;
            xT[((size_t)(d * 256 + c)) * 32 + b] = acc[i][j];
        }
}

// ---------------- avg (2-stage) ----------------
__global__ __launch_bounds__(256) void avg_part(const float* __restrict__ emb,
                                                const int* __restrict__ imask,
                                                float* __restrict__ avp,
                                                float* __restrict__ avc) {
    const int bg = blockIdx.x;         // b*8+g
    const int b = bg >> 3, g = bg & 7;
    const int t = threadIdx.x;
    __shared__ int mk[64];
    if (t < 64) mk[t] = imask[b * L + g * 64 + t];
    __syncthreads();
    float s = 0.f;
#pragma unroll 4
    for (int i = 0; i < 64; ++i)
        if (mk[i]) s += emb[((size_t)b * L + g * 64 + i) * 256 + t];
    avp[(size_t)bg * 256 + t] = s;
    if (t == 0) {
        int c = 0;
#pragma unroll
        for (int i = 0; i < 64; ++i) c += (mk[i] != 0);
        avc[bg] = (float)c;
    }
}

__global__ __launch_bounds__(256) void avg_comb(const float* __restrict__ avp,
                                                const float* __restrict__ avc,
                                                float* __restrict__ xT) {
    const int b = blockIdx.x;
    const int t = threadIdx.x;
    float s = 0.f, c = 0.f;
#pragma unroll
    for (int g = 0; g < 8; ++g) {
        s += avp[(size_t)(b * 8 + g) * 256 + t];
        c += avc[b * 8 + g];
    }
    xT[((size_t)(D * H * DV + t)) * 32 + b] = s / fmaxf(c, 1.f);
}

// ---------------- split-K fc, fixed trip count ----------------
template<int CH>
__global__ __launch_bounds__(256) void fcsplit(const float* __restrict__ xT,
                                               const float* __restrict__ Wf,
                                               float* __restrict__ part,
                                               int ncols) {
    const int ct = blockIdx.x;
    const int kc = blockIdx.y;
    const int t = threadIdx.x;
    const int col0 = ct * 512 + 2 * t;
    const size_t k0 = (size_t)kc * CH;
    __shared__ float xs[CH][32];
    float acc0[32], acc1[32];
#pragma unroll
    for (int b = 0; b < 32; ++b) { acc0[b] = 0.f; acc1[b] = 0.f; }

    const float4* src = reinterpret_cast<const float4*>(xT + k0 * 32);
    float4* dst = reinterpret_cast<float4*>(&xs[0][0]);
#pragma unroll
    for (int i = 0; i < CH * 8 / 256; ++i) dst[t + i * 256] = src[t + i * 256];
    __syncthreads();

    const float* wp = Wf + k0 * ncols + col0;
#pragma unroll 8
    for (int kk = 0; kk < CH; ++kk) {
        float2 wv = *reinterpret_cast<const float2*>(wp + (size_t)kk * ncols);
        const float4* xr = reinterpret_cast<const float4*>(xs[kk]);
#pragma unroll
        for (int i = 0; i < 8; ++i) {
            float4 xv = xr[i];
            acc0[i*4+0] += xv.x * wv.x; acc0[i*4+1] += xv.y * wv.x;
            acc0[i*4+2] += xv.z * wv.x; acc0[i*4+3] += xv.w * wv.x;
            acc1[i*4+0] += xv.x * wv.y; acc1[i*4+1] += xv.y * wv.y;
            acc1[i*4+2] += xv.z * wv.y; acc1[i*4+3] += xv.w * wv.y;
        }
    }
    float* pp = part + (size_t)kc * 32 * ncols;
#pragma unroll
    for (int b = 0; b < 32; ++b) {
        float2 o; o.x = acc0[b]; o.y = acc1[b];
        *reinterpret_cast<float2*>(&pp[(size_t)b * ncols + col0]) = o;
    }
}

// ---------------- reduce partials -> out^T (ncols x 32), bias + relu ----------------
__global__ __launch_bounds__(256) void fcreduce_kernel(const float* __restrict__ part,
                                                       const float* __restrict__ bias,
                                                       float* __restrict__ outT,
                                                       int nkc) {
    const int o = blockIdx.x * 256 + threadIdx.x;
    float s = 0.f;
    for (int kc = 0; kc < nkc; ++kc) s += part[(size_t)kc * 65536 + o];
    const int b = o >> 11, col = o & 2047;
    s += bias[col];
    s = fmaxf(s, 0.f);
    outT[(size_t)col * 32 + b] = s;
}

// ---------------- fc3 ----------------
__global__ __launch_bounds__(256) void fc3_kernel(const float* __restrict__ h2T,
                                                  const float* __restrict__ w3,
                                                  const float* __restrict__ b3,
                                                  float* __restrict__ out) {
    const int t = threadIdx.x;
    const int b = t & 31, p = t >> 5;
    float s = 0.f;
    for (int k = p; k < DFF; k += 8) s += h2T[(size_t)k * 32 + b] * w3[k];
    __shared__ float red[8][32];
    red[p][b] = s;
    __syncthreads();
    if (t < 32) {
        float tot = 0.f;
#pragma unroll
        for (int q = 0; q < 8; ++q) tot += red[q][t];
        out[t] = tot + b3[0];
    }
}

extern "C" void kernel_launch(void* const* d_in, const int* in_sizes, int n_in,
                              void* d_out, int out_size, void* d_ws, size_t ws_size,
                              hipStream_t stream) {
    const float* emb   = (const float*)d_in[0];
    const int*   amask = (const int*)d_in[1];
    const int*   imask = (const int*)d_in[2];
    const float* WQ    = (const float*)d_in[3];
    const float* WK    = (const float*)d_in[4];
    const float* WV    = (const float*)d_in[5];
    const float* fc1w  = (const float*)d_in[6];
    const float* fc1b  = (const float*)d_in[7];
    const float* fc2w  = (const float*)d_in[8];
    const float* fc2b  = (const float*)d_in[9];
    const float* fc3w  = (const float*)d_in[10];
    const float* fc3b  = (const float*)d_in[11];

    float* out_head = (float*)d_out;
    float* attn_out = out_head + 32;

    float* ws = (float*)d_ws;
    // Layout (floats). part1 (67 MB) aliases the Q/K/V/ctx/wts region, which is
    // dead by the time fc1 runs. Peak usage ~86 MB (< the 110 MB known-good).
    const size_t OFF_XT = 0;                       // 65792*32 = 2,105,344
    const size_t OFF_U  = 2105344;                 // union region, 257*65536 = 16,842,752
    const size_t OFF_H1 = OFF_U + 16842752;        // h1T: 65,536
    const size_t OFF_P2 = OFF_H1 + 65536;          // part2: 64*65536 = 4,194,304 -> only 64 chunks*65536 = 4,194,304? (64*65536=4,194,304)
    const size_t OFF_H2 = OFF_P2 + 4194304;        // h2T: 65,536
    const size_t OFF_MB = OFF_H2 + 65536;          // mask bits: 262,144 u32
    const size_t OFF_AVP = OFF_MB + 262144;        // avg partials: 65,536 + 256

    float* xT    = ws + OFF_XT;
    __hip_bfloat16* Qb = (__hip_bfloat16*)(ws + OFF_U);
    __hip_bfloat16* Kb = (__hip_bfloat16*)(ws + OFF_U + 2097152);
    __hip_bfloat16* Vt = (__hip_bfloat16*)(ws + OFF_U + 4194304);
    float* ctx   = ws + OFF_U + 6291456;
    float* wtsb  = ws + OFF_U + 10485760;
    float* part1 = ws + OFF_U;                     // aliases the above (all dead by fc1)
    float* h1T   = ws + OFF_H1;
    float* part2 = ws + OFF_P2;
    float* h2T   = ws + OFF_H2;
    unsigned int* mbits = (unsigned int*)(ws + OFF_MB);
    float* avp   = ws + OFF_AVP;
    float* avc   = ws + OFF_AVP + 65536;

    maskpack<<<dim3(32768), 256, 0, stream>>>(amask, mbits);
    proj_fused<<<dim3(512), 256, 0, stream>>>(emb, WQ, WK, WV, Qb, Kb, Vt);
    attn_mfma<<<dim3(8, BH), 256, 0, stream>>>(Qb, Kb, Vt, mbits, attn_out, ctx);
    wts_kernel<<<dim3(B * 4), 256, 0, stream>>>(ctx, imask, wtsb);
    pooled_kernel<<<dim3(4, 4, B), 256, 0, stream>>>(emb, wtsb, xT);
    avg_part<<<dim3(B * 8), 256, 0, stream>>>(emb, imask, avp, avc);
    avg_comb<<<dim3(B), 256, 0, stream>>>(avp, avc, xT);

    fcsplit<256><<<dim3(4, 257), 256, 0, stream>>>(xT, fc1w, part1, DFF);
    fcreduce_kernel<<<dim3(256), 256, 0, stream>>>(part1, fc1b, h1T, 257);

    fcsplit<32><<<dim3(4, 64), 256, 0, stream>>>(h1T, fc2w, part2, DFF);
    fcreduce_kernel<<<dim3(256), 256, 0, stream>>>(part2, fc2b, h2T, 64);

    fc3_kernel<<<dim3(1), 256, 0, stream>>>(h2T, fc3w, fc3b, out_head);
}

// Round 5
// 617.280 us; speedup vs baseline: 3.4597x; 1.4904x over previous
//
#include <hip/hip_runtime.h>
#include <hip/hip_bf16.h>
#include <cstdint>

namespace {
constexpr int B  = 32;
constexpr int L  = 512;
constexpr int D  = 256;
constexpr int H  = 8;
constexpr int DV = 32;
constexpr int DFF = 2048;
constexpr int CONCAT = D * H * DV + D;   // 65792
constexpr int BH = B * H;                // 256
}

typedef __attribute__((ext_vector_type(8))) short bf16x8;
typedef __attribute__((ext_vector_type(4))) float f32x4;

static __device__ __forceinline__ unsigned short f2bf_bits(float x) {
    __hip_bfloat16 h = __float2bfloat16(x);
    return *reinterpret_cast<unsigned short*>(&h);
}
static __device__ __forceinline__ float bf2f(short u) {
    unsigned int x = ((unsigned int)(unsigned short)u) << 16;
    union { unsigned int u; float f; } c; c.u = x; return c.f;
}
static __device__ __forceinline__ bf16x8 pack8(const float* v) {
    bf16x8 r;
#pragma unroll
    for (int j = 0; j < 8; ++j) r[j] = (short)f2bf_bits(v[j]);
    return r;
}

// ---------------- mask bit-pack ----------------
__global__ __launch_bounds__(256) void maskpack(const int* __restrict__ amask,
                                                unsigned int* __restrict__ mb) {
    const int t = threadIdx.x;
    const size_t gid = (size_t)blockIdx.x * 256 + t;
    int v = amask[gid];
    unsigned long long bal = __ballot(v != 0);
    if ((t & 63) == 0) *reinterpret_cast<unsigned long long*>(mb + (gid >> 5)) = bal;
}

// ---------------- QKV projection via MFMA (no LDS) ----------------
__global__ __launch_bounds__(256) void proj_mfma(const float* __restrict__ emb,
                                                 const float* __restrict__ WQ,
                                                 const float* __restrict__ WK,
                                                 const float* __restrict__ WV,
                                                 __hip_bfloat16* __restrict__ Qb,
                                                 __hip_bfloat16* __restrict__ Kb,
                                                 __hip_bfloat16* __restrict__ Vt) {
    const int rb = blockIdx.x * 32;
    const int t = threadIdx.x;
    const int w = t >> 6, l = t & 63;
    const int lr = l & 15, lg = l >> 4;

    f32x4 accQ[2][4], accK[2][4], accV[2][4];
#pragma unroll
    for (int m = 0; m < 2; ++m)
#pragma unroll
        for (int n = 0; n < 4; ++n) {
            accQ[m][n] = (f32x4){0.f,0.f,0.f,0.f};
            accK[m][n] = (f32x4){0.f,0.f,0.f,0.f};
            accV[m][n] = (f32x4){0.f,0.f,0.f,0.f};
        }

    for (int kc = 0; kc < 8; ++kc) {
        const int k0 = kc * 32 + lg * 8;
        bf16x8 a[2];
#pragma unroll
        for (int m = 0; m < 2; ++m) {
            const float* ap = emb + (size_t)(rb + m * 16 + lr) * 256 + k0;
            float av[8];
#pragma unroll
            for (int j = 0; j < 8; ++j) av[j] = ap[j];
            a[m] = pack8(av);
        }
#pragma unroll
        for (int nt = 0; nt < 4; ++nt) {
            const int col = w * 64 + nt * 16 + lr;
            float wv[8];
#pragma unroll
            for (int j = 0; j < 8; ++j) wv[j] = WQ[(size_t)(k0 + j) * 256 + col];
            bf16x8 bw = pack8(wv);
            accQ[0][nt] = __builtin_amdgcn_mfma_f32_16x16x32_bf16(a[0], bw, accQ[0][nt], 0, 0, 0);
            accQ[1][nt] = __builtin_amdgcn_mfma_f32_16x16x32_bf16(a[1], bw, accQ[1][nt], 0, 0, 0);
#pragma unroll
            for (int j = 0; j < 8; ++j) wv[j] = WK[(size_t)(k0 + j) * 256 + col];
            bw = pack8(wv);
            accK[0][nt] = __builtin_amdgcn_mfma_f32_16x16x32_bf16(a[0], bw, accK[0][nt], 0, 0, 0);
            accK[1][nt] = __builtin_amdgcn_mfma_f32_16x16x32_bf16(a[1], bw, accK[1][nt], 0, 0, 0);
#pragma unroll
            for (int j = 0; j < 8; ++j) wv[j] = WV[(size_t)(k0 + j) * 256 + col];
            bw = pack8(wv);
            accV[0][nt] = __builtin_amdgcn_mfma_f32_16x16x32_bf16(a[0], bw, accV[0][nt], 0, 0, 0);
            accV[1][nt] = __builtin_amdgcn_mfma_f32_16x16x32_bf16(a[1], bw, accV[1][nt], 0, 0, 0);
        }
    }

    const int b = rb >> 9, l0 = rb & 511;
#pragma unroll
    for (int m = 0; m < 2; ++m)
#pragma unroll
        for (int nt = 0; nt < 4; ++nt) {
            const int n = w * 64 + nt * 16 + lr;
            const int h = n >> 5, d = n & 31;
            const int bh = b * 8 + h;
#pragma unroll
            for (int r = 0; r < 4; ++r) {
                const int ll = l0 + m * 16 + lg * 4 + r;
                Qb[((size_t)bh * 512 + ll) * 32 + d] = __float2bfloat16(accQ[m][nt][r]);
                Kb[((size_t)bh * 512 + ll) * 32 + d] = __float2bfloat16(accK[m][nt][r]);
                Vt[((size_t)bh * 32 + d) * 512 + ll] = __float2bfloat16(accV[m][nt][r]);
            }
        }
}

// ---------------- MFMA attention (hardened: explicit barriers, shuffle rinv broadcast) ----------------
__global__ __launch_bounds__(256, 2) void attn_mfma(const __hip_bfloat16* __restrict__ Q,
                                                    const __hip_bfloat16* __restrict__ K,
                                                    const __hip_bfloat16* __restrict__ Vt,
                                                    const unsigned int* __restrict__ mb,
                                                    float* __restrict__ attn_out,
                                                    float* __restrict__ ctx) {
    const int qt = blockIdx.x;
    const int bh = blockIdx.y;
    const int b = bh >> 3, h = bh & 7;
    const int t = threadIdx.x;
    const int w = t >> 6, l = t & 63;
    const int lr = l & 15, lg = l >> 4;
    const int q0 = qt * 64 + w * 16;

    __shared__ __hip_bfloat16 Pl[4][16][40];

    const float scale = 0.17677669529663687f;

    const bf16x8 aq = *reinterpret_cast<const bf16x8*>(Q + ((size_t)bh * L + q0 + lr) * 32 + lg * 8);

    f32x4 sc[32];
    const __hip_bfloat16* Kbase = K + (size_t)bh * L * 32;
#pragma unroll
    for (int kt = 0; kt < 32; ++kt) {
        bf16x8 bk = *reinterpret_cast<const bf16x8*>(Kbase + (size_t)(kt * 16 + lr) * 32 + lg * 8);
        sc[kt] = __builtin_amdgcn_mfma_f32_16x16x32_bf16(aq, bk, (f32x4){0.f,0.f,0.f,0.f}, 0, 0, 0);
    }

    float rin[4];
#pragma unroll
    for (int r = 0; r < 4; ++r) {
        const int q = q0 + lg * 4 + r;
        const uint4* mrow = reinterpret_cast<const uint4*>(mb + ((size_t)b * L + q) * 16);
        uint4 m0 = mrow[0], m1 = mrow[1], m2 = mrow[2], m3 = mrow[3];
        const unsigned int wds[16] = {m0.x, m0.y, m0.z, m0.w, m1.x, m1.y, m1.z, m1.w,
                                      m2.x, m2.y, m2.z, m2.w, m3.x, m3.y, m3.z, m3.w};
        float mx = -3.4e38f;
#pragma unroll
        for (int kt = 0; kt < 32; ++kt) {
            unsigned bit = (unsigned)lr + ((kt & 1) << 4);
            float s = ((wds[kt >> 1] >> bit) & 1u) ? -1e9f : sc[kt][r] * scale;
            sc[kt][r] = s;
            mx = fmaxf(mx, s);
        }
        mx = fmaxf(mx, __shfl_xor(mx, 1));
        mx = fmaxf(mx, __shfl_xor(mx, 2));
        mx = fmaxf(mx, __shfl_xor(mx, 4));
        mx = fmaxf(mx, __shfl_xor(mx, 8));
        float sum = 0.f;
#pragma unroll
        for (int kt = 0; kt < 32; ++kt) {
            float e = __expf(sc[kt][r] - mx);
            sc[kt][r] = e;
            sum += e;
        }
        sum += __shfl_xor(sum, 1);
        sum += __shfl_xor(sum, 2);
        sum += __shfl_xor(sum, 4);
        sum += __shfl_xor(sum, 8);
        rin[r] = 1.f / sum;
    }
    // rinv for row lr (race-free cross-lane broadcast: rin[r] is uniform within
    // each 16-lane group lg and holds row q0+lg*4+r; row lr lives in group lr>>2)
    const int srcl = (lr >> 2) * 16;
    const float v0 = __shfl(rin[0], srcl);
    const float v1 = __shfl(rin[1], srcl);
    const float v2 = __shfl(rin[2], srcl);
    const float v3 = __shfl(rin[3], srcl);
    const int sel = lr & 3;
    const float my_ri = (sel == 0) ? v0 : (sel == 1) ? v1 : (sel == 2) ? v2 : v3;

    // ---- PV + fused normalized-attn store (explicit barriers around LDS transpose) ----
    f32x4 acc0 = {0.f,0.f,0.f,0.f}, acc1 = {0.f,0.f,0.f,0.f};
    const __hip_bfloat16* Vb = Vt + (size_t)bh * 32 * L;
    float* aob = attn_out + ((size_t)bh * L + q0 + lr) * L;
#pragma unroll
    for (int c = 0; c < 16; ++c) {
#pragma unroll
        for (int r = 0; r < 4; ++r) {
            Pl[w][lg * 4 + r][lr]      = __float2bfloat16(sc[2*c  ][r]);
            Pl[w][lg * 4 + r][16 + lr] = __float2bfloat16(sc[2*c+1][r]);
        }
        __syncthreads();   // writes visible before reads (uniform across block)
        bf16x8 ap  = *reinterpret_cast<const bf16x8*>(&Pl[w][lr][lg * 8]);
        float4 o0, o1;
        o0.x = bf2f(ap[0]) * my_ri; o0.y = bf2f(ap[1]) * my_ri;
        o0.z = bf2f(ap[2]) * my_ri; o0.w = bf2f(ap[3]) * my_ri;
        o1.x = bf2f(ap[4]) * my_ri; o1.y = bf2f(ap[5]) * my_ri;
        o1.z = bf2f(ap[6]) * my_ri; o1.w = bf2f(ap[7]) * my_ri;
        float* ao = aob + c * 32 + lg * 8;
        *reinterpret_cast<float4*>(ao)     = o0;
        *reinterpret_cast<float4*>(ao + 4) = o1;
        bf16x8 bv0 = *reinterpret_cast<const bf16x8*>(Vb + (size_t)lr        * L + c * 32 + lg * 8);
        bf16x8 bv1 = *reinterpret_cast<const bf16x8*>(Vb + (size_t)(16 + lr) * L + c * 32 + lg * 8);
        acc0 = __builtin_amdgcn_mfma_f32_16x16x32_bf16(ap, bv0, acc0, 0, 0, 0);
        acc1 = __builtin_amdgcn_mfma_f32_16x16x32_bf16(ap, bv1, acc1, 0, 0, 0);
        __syncthreads();   // reads done before next iteration's writes
    }
    float* cb = ctx + ((size_t)b * L + q0 + lg * 4) * 256 + h * 32;
#pragma unroll
    for (int r = 0; r < 4; ++r) {
        cb[r * 256 + lr]      = acc0[r] * rin[r];
        cb[r * 256 + 16 + lr] = acc1[r] * rin[r];
    }
}

// ---------------- column softmax over L for ctx -> weights (bf16 out) ----------------
__global__ __launch_bounds__(256) void wts_kernel(const float* __restrict__ ctx,
                                                  const int* __restrict__ imask,
                                                  __hip_bfloat16* __restrict__ wts) {
    const int b = blockIdx.x >> 2;
    const int ct = blockIdx.x & 3;
    const int t = threadIdx.x;
    const int c = ct * 64 + (t & 63);
    const int g = t >> 6;
    __shared__ float red[4][64];
    __shared__ int mk[L];
    for (int p = t; p < L; p += 256) mk[p] = imask[b * L + p];
    __syncthreads();

    float m = -3.4e38f;
    for (int ll = g; ll < L; ll += 4) {
        float v = mk[ll] ? ctx[((size_t)b * L + ll) * 256 + c] : -1e9f;
        m = fmaxf(m, v);
    }
    red[g][t & 63] = m;
    __syncthreads();
    m = fmaxf(fmaxf(red[0][t & 63], red[1][t & 63]), fmaxf(red[2][t & 63], red[3][t & 63]));

    float sum = 0.f;
    for (int ll = g; ll < L; ll += 4) {
        float v = mk[ll] ? ctx[((size_t)b * L + ll) * 256 + c] : -1e9f;
        sum += __expf(v - m);
    }
    __syncthreads();
    red[g][t & 63] = sum;
    __syncthreads();
    sum = red[0][t & 63] + red[1][t & 63] + red[2][t & 63] + red[3][t & 63];
    const float rinv = 1.f / sum;

    for (int ll = g; ll < L; ll += 4) {
        float v = mk[ll] ? ctx[((size_t)b * L + ll) * 256 + c] : -1e9f;
        wts[((size_t)b * L + ll) * 256 + c] = __float2bfloat16(__expf(v - m) * rinv);
    }
}

// ---------------- pooled via MFMA (no LDS) ----------------
__global__ __launch_bounds__(256) void pooled_mfma(const float* __restrict__ emb,
                                                   const __hip_bfloat16* __restrict__ wts,
                                                   __hip_bfloat16* __restrict__ xR) {
    const int ct = blockIdx.x, dt = blockIdx.y, b = blockIdx.z;
    const int t = threadIdx.x;
    const int w = t >> 6, l = t & 63;
    const int lr = l & 15, lg = l >> 4;
    const int wr = w >> 1, wc = w & 1;
    const int d0 = dt * 64 + wr * 32;
    const int c0 = ct * 64 + wc * 32;

    f32x4 acc[2][2];
#pragma unroll
    for (int m = 0; m < 2; ++m)
#pragma unroll
        for (int n = 0; n < 2; ++n) acc[m][n] = (f32x4){0.f,0.f,0.f,0.f};

    for (int lc = 0; lc < 16; ++lc) {
        const int lbase = lc * 32 + lg * 8;
        bf16x8 a[2], bb[2];
#pragma unroll
        for (int m = 0; m < 2; ++m) {
            float av[8];
#pragma unroll
            for (int j = 0; j < 8; ++j)
                av[j] = emb[((size_t)b * 512 + lbase + j) * 256 + d0 + m * 16 + lr];
            a[m] = pack8(av);
        }
#pragma unroll
        for (int n = 0; n < 2; ++n) {
            bf16x8 bw;
#pragma unroll
            for (int j = 0; j < 8; ++j) {
                __hip_bfloat16 hv = wts[((size_t)b * 512 + lbase + j) * 256 + c0 + n * 16 + lr];
                bw[j] = *reinterpret_cast<short*>(&hv);
            }
            bb[n] = bw;
        }
#pragma unroll
        for (int m = 0; m < 2; ++m)
#pragma unroll
            for (int n = 0; n < 2; ++n)
                acc[m][n] = __builtin_amdgcn_mfma_f32_16x16x32_bf16(a[m], bb[n], acc[m][n], 0, 0, 0);
    }
#pragma unroll
    for (int m = 0; m < 2; ++m)
#pragma unroll
        for (int n = 0; n < 2; ++n)
#pragma unroll
            for (int r = 0; r < 4; ++r) {
                const int d = d0 + m * 16 + lg * 4 + r;
                const int c = c0 + n * 16 + lr;
                xR[(size_t)b * CONCAT + d * 256 + c] = __float2bfloat16(acc[m][n][r]);
            }
}

// ---------------- avg (2-stage) -> xR tail ----------------
__global__ __launch_bounds__(256) void avg_part(const float* __restrict__ emb,
                                                const int* __restrict__ imask,
                                                float* __restrict__ avp,
                                                float* __restrict__ avc) {
    const int bg = blockIdx.x;
    const int b = bg >> 3, g = bg & 7;
    const int t = threadIdx.x;
    __shared__ int mk[64];
    if (t < 64) mk[t] = imask[b * L + g * 64 + t];
    __syncthreads();
    float s = 0.f;
#pragma unroll 4
    for (int i = 0; i < 64; ++i)
        if (mk[i]) s += emb[((size_t)b * L + g * 64 + i) * 256 + t];
    avp[(size_t)bg * 256 + t] = s;
    if (t == 0) {
        int c = 0;
#pragma unroll
        for (int i = 0; i < 64; ++i) c += (mk[i] != 0);
        avc[bg] = (float)c;
    }
}

__global__ __launch_bounds__(256) void avg_comb(const float* __restrict__ avp,
                                                const float* __restrict__ avc,
                                                __hip_bfloat16* __restrict__ xR) {
    const int b = blockIdx.x;
    const int t = threadIdx.x;
    float s = 0.f, c = 0.f;
#pragma unroll
    for (int g = 0; g < 8; ++g) {
        s += avp[(size_t)(b * 8 + g) * 256 + t];
        c += avc[b * 8 + g];
    }
    xR[(size_t)b * CONCAT + 65536 + t] = __float2bfloat16(s / fmaxf(c, 1.f));
}

// ---------------- fc1 via MFMA (no LDS) ----------------
template<int KSTEPS>
__global__ __launch_bounds__(256) void fc_mfma(const __hip_bfloat16* __restrict__ xR,
                                               const float* __restrict__ Wf,
                                               float* __restrict__ part,
                                               int kcbase) {
    const int bx = blockIdx.x;
    const int kc = blockIdx.y + kcbase;
    const int kbase = kc * 512;
    const int t = threadIdx.x;
    const int w = t >> 6, l = t & 63;
    const int lr = l & 15, lg = l >> 4;
    const int col0 = bx * 256 + w * 64;

    f32x4 acc[2][4];
#pragma unroll
    for (int m = 0; m < 2; ++m)
#pragma unroll
        for (int n = 0; n < 4; ++n) acc[m][n] = (f32x4){0.f,0.f,0.f,0.f};

    for (int kt = 0; kt < KSTEPS; ++kt) {
        const int k = kbase + kt * 32 + lg * 8;
        bf16x8 a0 = *reinterpret_cast<const bf16x8*>(xR + (size_t)lr * CONCAT + k);
        bf16x8 a1 = *reinterpret_cast<const bf16x8*>(xR + (size_t)(16 + lr) * CONCAT + k);
#pragma unroll
        for (int nt = 0; nt < 4; ++nt) {
            const float* wp = Wf + (size_t)k * 2048 + col0 + nt * 16 + lr;
            float wv[8];
#pragma unroll
            for (int j = 0; j < 8; ++j) wv[j] = wp[(size_t)j * 2048];
            bf16x8 bw = pack8(wv);
            acc[0][nt] = __builtin_amdgcn_mfma_f32_16x16x32_bf16(a0, bw, acc[0][nt], 0, 0, 0);
            acc[1][nt] = __builtin_amdgcn_mfma_f32_16x16x32_bf16(a1, bw, acc[1][nt], 0, 0, 0);
        }
    }
    float* pp = part + (size_t)kc * 65536;
#pragma unroll
    for (int m = 0; m < 2; ++m)
#pragma unroll
        for (int nt = 0; nt < 4; ++nt)
#pragma unroll
            for (int r = 0; r < 4; ++r) {
                const int bb = m * 16 + lg * 4 + r;
                pp[(size_t)bb * 2048 + col0 + nt * 16 + lr] = acc[m][nt][r];
            }
}

// ---------------- reduce partials -> out^T (2048 x 32), bias + relu ----------------
__global__ __launch_bounds__(256) void fcreduce_kernel(const float* __restrict__ part,
                                                       const float* __restrict__ bias,
                                                       float* __restrict__ outT,
                                                       int nkc) {
    const int o = blockIdx.x * 256 + threadIdx.x;
    float s = 0.f;
    for (int kc = 0; kc < nkc; ++kc) s += part[(size_t)kc * 65536 + o];
    const int b = o >> 11, col = o & 2047;
    s += bias[col];
    s = fmaxf(s, 0.f);
    outT[(size_t)col * 32 + b] = s;
}

// ---------------- fp32 split-K fc (fc2) ----------------
template<int CH>
__global__ __launch_bounds__(256) void fcsplit(const float* __restrict__ xT,
                                               const float* __restrict__ Wf,
                                               float* __restrict__ part,
                                               int ncols) {
    const int ct = blockIdx.x;
    const int kc = blockIdx.y;
    const int t = threadIdx.x;
    const int col0 = ct * 512 + 2 * t;
    const size_t k0 = (size_t)kc * CH;
    __shared__ float xs[CH][32];
    float acc0[32], acc1[32];
#pragma unroll
    for (int b = 0; b < 32; ++b) { acc0[b] = 0.f; acc1[b] = 0.f; }

    const float4* src = reinterpret_cast<const float4*>(xT + k0 * 32);
    float4* dst = reinterpret_cast<float4*>(&xs[0][0]);
#pragma unroll
    for (int i = 0; i < CH * 8 / 256; ++i) dst[t + i * 256] = src[t + i * 256];
    __syncthreads();

    const float* wp = Wf + k0 * ncols + col0;
#pragma unroll 8
    for (int kk = 0; kk < CH; ++kk) {
        float2 wv = *reinterpret_cast<const float2*>(wp + (size_t)kk * ncols);
        const float4* xr = reinterpret_cast<const float4*>(xs[kk]);
#pragma unroll
        for (int i = 0; i < 8; ++i) {
            float4 xv = xr[i];
            acc0[i*4+0] += xv.x * wv.x; acc0[i*4+1] += xv.y * wv.x;
            acc0[i*4+2] += xv.z * wv.x; acc0[i*4+3] += xv.w * wv.x;
            acc1[i*4+0] += xv.x * wv.y; acc1[i*4+1] += xv.y * wv.y;
            acc1[i*4+2] += xv.z * wv.y; acc1[i*4+3] += xv.w * wv.y;
        }
    }
    float* pp = part + (size_t)kc * 32 * ncols;
#pragma unroll
    for (int b = 0; b < 32; ++b) {
        float2 o; o.x = acc0[b]; o.y = acc1[b];
        *reinterpret_cast<float2*>(&pp[(size_t)b * ncols + col0]) = o;
    }
}

// ---------------- fc3 ----------------
__global__ __launch_bounds__(256) void fc3_kernel(const float* __restrict__ h2T,
                                                  const float* __restrict__ w3,
                                                  const float* __restrict__ b3,
                                                  float* __restrict__ out) {
    const int t = threadIdx.x;
    const int b = t & 31, p = t >> 5;
    float s = 0.f;
    for (int k = p; k < DFF; k += 8) s += h2T[(size_t)k * 32 + b] * w3[k];
    __shared__ float red[8][32];
    red[p][b] = s;
    __syncthreads();
    if (t < 32) {
        float tot = 0.f;
#pragma unroll
        for (int q = 0; q < 8; ++q) tot += red[q][t];
        out[t] = tot + b3[0];
    }
}

extern "C" void kernel_launch(void* const* d_in, const int* in_sizes, int n_in,
                              void* d_out, int out_size, void* d_ws, size_t ws_size,
                              hipStream_t stream) {
    const float* emb   = (const float*)d_in[0];
    const int*   amask = (const int*)d_in[1];
    const int*   imask = (const int*)d_in[2];
    const float* WQ    = (const float*)d_in[3];
    const float* WK    = (const float*)d_in[4];
    const float* WV    = (const float*)d_in[5];
    const float* fc1w  = (const float*)d_in[6];
    const float* fc1b  = (const float*)d_in[7];
    const float* fc2w  = (const float*)d_in[8];
    const float* fc2b  = (const float*)d_in[9];
    const float* fc3w  = (const float*)d_in[10];
    const float* fc3b  = (const float*)d_in[11];

    float* out_head = (float*)d_out;
    float* attn_out = out_head + 32;

    float* ws = (float*)d_ws;
    // FULLY DISJOINT layout (float units) — no aliasing. Total 26,743,040 floats
    // = 107 MB (< 118.3 MB proven available in round 1).
    const size_t OFF_XR  = 0;                         // xR bf16: 1,052,672 floats
    const size_t OFF_Q   = OFF_XR + 1052672;          // Qb bf16: 2,097,152
    const size_t OFF_K   = OFF_Q + 2097152;           // Kb bf16: 2,097,152
    const size_t OFF_V   = OFF_K + 2097152;           // Vt bf16: 2,097,152
    const size_t OFF_CTX = OFF_V + 2097152;           // ctx fp32: 4,194,304
    const size_t OFF_WTS = OFF_CTX + 4194304;         // wts bf16: 2,097,152
    const size_t OFF_P1  = OFF_WTS + 2097152;         // part1: 129*65536 = 8,454,144
    const size_t OFF_H1  = OFF_P1 + 8454144;          // h1T: 65,536
    const size_t OFF_P2  = OFF_H1 + 65536;            // part2: 64*65536 = 4,194,304
    const size_t OFF_H2  = OFF_P2 + 4194304;          // h2T: 65,536
    const size_t OFF_MB  = OFF_H2 + 65536;            // mask bits: 262,144 u32
    const size_t OFF_AVP = OFF_MB + 262144;           // avg partials: 65,536 + 256

    __hip_bfloat16* xR = (__hip_bfloat16*)(ws + OFF_XR);
    __hip_bfloat16* Qb = (__hip_bfloat16*)(ws + OFF_Q);
    __hip_bfloat16* Kb = (__hip_bfloat16*)(ws + OFF_K);
    __hip_bfloat16* Vt = (__hip_bfloat16*)(ws + OFF_V);
    float* ctx   = ws + OFF_CTX;
    __hip_bfloat16* wtsb = (__hip_bfloat16*)(ws + OFF_WTS);
    float* part1 = ws + OFF_P1;
    float* h1T   = ws + OFF_H1;
    float* part2 = ws + OFF_P2;
    float* h2T   = ws + OFF_H2;
    unsigned int* mbits = (unsigned int*)(ws + OFF_MB);
    float* avp   = ws + OFF_AVP;
    float* avc   = ws + OFF_AVP + 65536;

    maskpack<<<dim3(32768), 256, 0, stream>>>(amask, mbits);
    proj_mfma<<<dim3(512), 256, 0, stream>>>(emb, WQ, WK, WV, Qb, Kb, Vt);
    attn_mfma<<<dim3(8, BH), 256, 0, stream>>>(Qb, Kb, Vt, mbits, attn_out, ctx);
    wts_kernel<<<dim3(B * 4), 256, 0, stream>>>(ctx, imask, wtsb);
    pooled_mfma<<<dim3(4, 4, B), 256, 0, stream>>>(emb, wtsb, xR);
    avg_part<<<dim3(B * 8), 256, 0, stream>>>(emb, imask, avp, avc);
    avg_comb<<<dim3(B), 256, 0, stream>>>(avp, avc, xR);

    // fc1: 128 full 512-chunks + one 256 tail (129 partial slots)
    fc_mfma<16><<<dim3(8, 128), 256, 0, stream>>>(xR, fc1w, part1, 0);
    fc_mfma<8><<<dim3(8, 1), 256, 0, stream>>>(xR, fc1w, part1, 128);
    fcreduce_kernel<<<dim3(256), 256, 0, stream>>>(part1, fc1b, h1T, 129);

    fcsplit<32><<<dim3(4, 64), 256, 0, stream>>>(h1T, fc2w, part2, DFF);
    fcreduce_kernel<<<dim3(256), 256, 0, stream>>>(part2, fc2b, h2T, 64);

    fc3_kernel<<<dim3(1), 256, 0, stream>>>(h2T, fc3w, fc3b, out_head);
}